// Round 7
// baseline (182.313 us; speedup 1.0000x reference)
//
#include <hip/hip_runtime.h>

// ---------------------------------------------------------------------------
// WRGCN round 7:
//  - gemm tile 128->64 rows/block (2x blocks: grid-limited occupancy 19->38%)
//  - 2-deep B-fragment prefetch (3-buffer rotation) to cover L2 latency
//  - agg: 2-deep row pipeline (prefetch next edge's row while accumulating)
//  (fillBufferAligned in profile = harness one-time d_ws poison; not ours)
// ---------------------------------------------------------------------------

#define DIM 128

typedef short short8 __attribute__((ext_vector_type(8)));
typedef float f32x4 __attribute__((ext_vector_type(4)));

__device__ __forceinline__ unsigned short f2bf(float f) {
    unsigned u = __float_as_uint(f);
    unsigned r = (u + 0x7FFFu + ((u >> 16) & 1u)) >> 16;   // RNE
    return (unsigned short)r;
}
__device__ __forceinline__ float bflo(unsigned p) { return __uint_as_float(p << 16); }
__device__ __forceinline__ float bfhi(unsigned p) { return __uint_as_float(p & 0xFFFF0000u); }

// ---------------- zero counts (int4 stores) --------------------------------
__global__ void zero_kernel(int4* __restrict__ p, int n4) {
    int i = blockIdx.x * 256 + threadIdx.x;
    if (i < n4) p[i] = make_int4(0, 0, 0, 0);
}

// ---------------- fat kernel 1: conv_bf16 | prep_w | count+rank ------------
#define K2_CONVB 2048
#define K2_PREPB 256
#define K2_CNTB  512

__device__ void conv_body(const float* __restrict__ in, unsigned short* __restrict__ ob,
                          int n8, int bid) {
    for (int i = bid * 256 + threadIdx.x; i < n8; i += K2_CONVB * 256) {
        const float4* ip = reinterpret_cast<const float4*>(in) + (size_t)i * 2;
        float4 v0 = ip[0], v1 = ip[1];
        uint4 o;
        o.x = (unsigned)f2bf(v0.x) | ((unsigned)f2bf(v0.y) << 16);
        o.y = (unsigned)f2bf(v0.z) | ((unsigned)f2bf(v0.w) << 16);
        o.z = (unsigned)f2bf(v1.x) | ((unsigned)f2bf(v1.y) << 16);
        o.w = (unsigned)f2bf(v1.z) | ((unsigned)f2bf(v1.w) << 16);
        reinterpret_cast<uint4*>(ob)[i] = o;
    }
}

// WTf[l][slot][n][ks][lane][j]: value = W_slot[k = ks*32+(lane>>4)*8+j][col = n*16+(lane&15)]
// slot 0..2 = w_rel[r]; slot 3 = w_root (+ w_skip if l==0); slot 4 = w_skip
__device__ void prep_body(const float* __restrict__ w_rel, const float* __restrict__ w_root,
                          const float* __restrict__ w_skip, unsigned short* __restrict__ WTf,
                          int bid) {
    for (int i = bid * 256 + threadIdx.x; i < 2 * 5 * DIM * DIM; i += K2_PREPB * 256) {
        int j    = i & 7;
        int lane = (i >> 3) & 63;
        int ks   = (i >> 9) & 3;
        int n    = (i >> 11) & 7;
        int s    = (i >> 14) % 5;
        int l    = i / (5 * DIM * DIM);
        int col = n * 16 + (lane & 15);
        int k   = ks * 32 + (lane >> 4) * 8 + j;
        float v;
        if (s < 3)       v = w_rel[(((size_t)l * 3 + s) * DIM + k) * DIM + col];
        else if (s == 3) {
            v = w_root[((size_t)l * DIM + k) * DIM + col];
            if (l == 0) v += w_skip[((size_t)k) * DIM + col];
        } else           v = w_skip[((size_t)l * DIM + k) * DIM + col];
        WTf[i] = f2bf(v);
    }
}

__device__ void count_body(const int* __restrict__ dst, int* __restrict__ counts,
                           unsigned short* __restrict__ rank, int E, int bid) {
    for (int i = bid * 256 + threadIdx.x; i < E; i += K2_CNTB * 256) {
        int r = atomicAdd(&counts[dst[i]], 1);
        rank[i] = (unsigned short)r;
    }
}

__global__ __launch_bounds__(256) void fat_prep(
    const float* __restrict__ x, unsigned short* __restrict__ xb, int n8,
    const float* __restrict__ w_rel, const float* __restrict__ w_root,
    const float* __restrict__ w_skip, unsigned short* __restrict__ WTf,
    const int* __restrict__ dst, int* __restrict__ counts,
    unsigned short* __restrict__ rank, int E) {
    int b = blockIdx.x;
    if (b < K2_CONVB)                 conv_body(x, xb, n8, b);
    else if (b < K2_CONVB + K2_PREPB) prep_body(w_rel, w_root, w_skip, WTf, b - K2_CONVB);
    else                              count_body(dst, counts, rank, E, b - K2_CONVB - K2_PREPB);
}

// ---------------- scan ------------------------------------------------------
__global__ void bsum_kernel(const int* __restrict__ counts, int* __restrict__ bsums, int n) {
    int t = threadIdx.x;
    int i = blockIdx.x * 256 + t;
    int v = (i < n) ? counts[i] : 0;
    for (int d = 32; d; d >>= 1) v += __shfl_down(v, d);
    __shared__ int ws[4];
    if ((t & 63) == 0) ws[t >> 6] = v;
    __syncthreads();
    if (t == 0) bsums[blockIdx.x] = ws[0] + ws[1] + ws[2] + ws[3];
}

__global__ void bscan_kernel(const int* __restrict__ bsums, int* __restrict__ bpre, int nblk) {
    __shared__ int s[256];
    int t = threadIdx.x;
    int v = (t < nblk) ? bsums[t] : 0;
    s[t] = v;
    __syncthreads();
    for (int d = 1; d < 256; d <<= 1) {
        int u = (t >= d) ? s[t - d] : 0;
        __syncthreads();
        s[t] += u;
        __syncthreads();
    }
    bpre[t] = s[t] - v;
}

__global__ void scan_final(const int* __restrict__ counts, const int* __restrict__ bpre,
                           int* __restrict__ offsets, int n, int E) {
    __shared__ int s[256];
    int t = threadIdx.x;
    int i = blockIdx.x * 256 + t;
    int v = (i < n) ? counts[i] : 0;
    s[t] = v;
    __syncthreads();
    for (int d = 1; d < 256; d <<= 1) {
        int u = (t >= d) ? s[t - d] : 0;
        __syncthreads();
        s[t] += u;
        __syncthreads();
    }
    int ex = s[t] - v + bpre[blockIdx.x];
    if (i < n) offsets[i] = ex;
    if (i == 0) offsets[n] = E;
}

// ---------------- LDS-free fused GEMM body ---------------------------------
// 4 waves x 16 rows = 64 rows/block. B-frags from fragment-linear WTf
// (L2-hot coalesced), 2-deep prefetch; A/X-frags direct bf16 loads.
template<bool HAS_SKIP>
__device__ void gemm_body(
    int bid,
    const unsigned short* __restrict__ Ab, const unsigned short* __restrict__ Xb,
    const unsigned short* __restrict__ WTf,
    const float* __restrict__ bconv, const float* __restrict__ bskip,
    unsigned short* __restrict__ hr, void* __restrict__ outp, int M) {
    constexpr int NF = HAS_SKIP ? 40 : 32;
    int t = threadIdx.x, lane = t & 63, wid = t >> 6;
    int lrow = lane & 15, lhi = lane >> 4;
    int r0 = bid * 64 + wid * 16;

    short8 af[4];
    {
        int r = r0 + lrow;
        const unsigned short* ap = Ab + (size_t)(r < M ? r : 0) * DIM + lhi * 8;
        #pragma unroll
        for (int ks = 0; ks < 4; ++ks)
            af[ks] = *reinterpret_cast<const short8*>(ap + ks * 32);
    }
    short8 xf[4];           // HAS_SKIP only (loaded at slot-3 entry)
    f32x4 acc34[8];         // HAS_SKIP: persists slot3 -> slot4

    short8 bb[3][4];        // 2-deep rotating B prefetch
    auto loadB = [&](int fi, short8* dstb) {
        const unsigned short* p = WTf + ((size_t)fi * 4 * 64 + lane) * 8;
        #pragma unroll
        for (int ks = 0; ks < 4; ++ks)
            dstb[ks] = *reinterpret_cast<const short8*>(p + ks * 512);
    };
    loadB(0, bb[0]);
    loadB(1, bb[1]);
    #pragma unroll
    for (int fi = 0; fi < NF; ++fi) {
        short8* bc = bb[fi % 3];
        if (fi + 2 < NF) loadB(fi + 2, bb[(fi + 2) % 3]);
        const int slot = fi >> 3, n = fi & 7;
        const int col = n * 16 + lrow;
        if (HAS_SKIP && slot == 3 && n == 0) {
            int r = r0 + lrow;
            const unsigned short* xp = Xb + (size_t)(r < M ? r : 0) * DIM + lhi * 8;
            #pragma unroll
            for (int ks = 0; ks < 4; ++ks)
                xf[ks] = *reinterpret_cast<const short8*>(xp + ks * 32);
        }
        if (slot < 3) {
            f32x4 a0 = {0.f, 0.f, 0.f, 0.f};
            #pragma unroll
            for (int ks = 0; ks < 4; ++ks)
                a0 = __builtin_amdgcn_mfma_f32_16x16x32_bf16(af[ks], bc[ks], a0, 0, 0, 0);
            unsigned short* hp = hr + (size_t)slot * M * DIM;
            #pragma unroll
            for (int i2 = 0; i2 < 4; ++i2) {
                int r = r0 + lhi * 4 + i2;
                if (r < M) hp[(size_t)r * DIM + col] = f2bf(a0[i2]);
            }
        } else if (!HAS_SKIP) {                    // layer 0, slot 3: store bf16 out
            f32x4 a0 = {0.f, 0.f, 0.f, 0.f};
            #pragma unroll
            for (int ks = 0; ks < 4; ++ks)
                a0 = __builtin_amdgcn_mfma_f32_16x16x32_bf16(af[ks], bc[ks], a0, 0, 0, 0);
            float bbias = bconv[col] + bskip[col];
            unsigned short* op = (unsigned short*)outp;
            #pragma unroll
            for (int i2 = 0; i2 < 4; ++i2) {
                int r = r0 + lhi * 4 + i2;
                if (r < M) op[(size_t)r * DIM + col] = f2bf(a0[i2] + bbias);
            }
        } else if (slot == 3) {                    // layer 1: hold root result
            f32x4 z = {0.f, 0.f, 0.f, 0.f};
            acc34[n] = z;
            #pragma unroll
            for (int ks = 0; ks < 4; ++ks)
                acc34[n] = __builtin_amdgcn_mfma_f32_16x16x32_bf16(af[ks], bc[ks], acc34[n], 0, 0, 0);
        } else {                                   // layer 1, slot 4: += skip, store f32
            #pragma unroll
            for (int ks = 0; ks < 4; ++ks)
                acc34[n] = __builtin_amdgcn_mfma_f32_16x16x32_bf16(xf[ks], bc[ks], acc34[n], 0, 0, 0);
            float bbias = bconv[col] + bskip[col];
            float* op = (float*)outp;
            #pragma unroll
            for (int i2 = 0; i2 < 4; ++i2) {
                int r = r0 + lhi * 4 + i2;
                if (r < M) op[(size_t)r * DIM + col] = acc34[n][i2] + bbias;
            }
        }
    }
}

// ---------------- fat kernel 2: gemm0 | scatter ----------------------------
#define K6_SCTB 512

// packed record: src(16) | rel(2)<<16 | wq(14)<<18, wq = round(w*16383)
__device__ void scatter_body(const int* __restrict__ src, const int* __restrict__ dst,
                             const int* __restrict__ etype, const float* __restrict__ ew,
                             const int* __restrict__ offsets,
                             const unsigned short* __restrict__ rank,
                             unsigned* __restrict__ csr, int E, int bid) {
    for (int i = bid * 256 + threadIdx.x; i < E; i += K6_SCTB * 256) {
        int d = dst[i];
        int p = offsets[d] + rank[i];
        unsigned wq = (unsigned)__float2uint_rn(ew[i] * 16383.0f);
        csr[p] = (unsigned)src[i] | ((unsigned)etype[i] << 16) | (wq << 18);
    }
}

__global__ __launch_bounds__(256) void gemm0_scatter(
    const unsigned short* __restrict__ Ab, const unsigned short* __restrict__ WTf,
    const float* __restrict__ bconv, const float* __restrict__ bskip,
    unsigned short* __restrict__ hr, unsigned short* __restrict__ h1, int M, int GB,
    const int* __restrict__ src, const int* __restrict__ dst,
    const int* __restrict__ etype, const float* __restrict__ ew,
    const int* __restrict__ offsets, const unsigned short* __restrict__ rank,
    unsigned* __restrict__ csr, int E) {
    int b = blockIdx.x;
    if (b < GB) gemm_body<false>(b, Ab, nullptr, WTf, bconv, bskip, hr, h1, M);
    else        scatter_body(src, dst, etype, ew, offsets, rank, csr, E, b - GB);
}

__global__ __launch_bounds__(256) void gemm1_kernel(
    const unsigned short* __restrict__ Ab, const unsigned short* __restrict__ Xb,
    const unsigned short* __restrict__ WTf,
    const float* __restrict__ bconv, const float* __restrict__ bskip,
    unsigned short* __restrict__ hr, float* __restrict__ outp, int M) {
    gemm_body<true>(blockIdx.x, Ab, Xb, WTf, bconv, bskip, hr, outp, M);
}

// ---------------- aggregation: 2-deep pipeline, 8 rows in flight/wave ------
// BF16IO: base/out buffer is bf16 (layer 0); else f32 (layer 1, d_out).
template<bool BF16IO>
__global__ __launch_bounds__(256) void agg_kernel(
    const unsigned short* __restrict__ hr, const unsigned* __restrict__ csr,
    const int* __restrict__ offsets, float* __restrict__ outf,
    unsigned short* __restrict__ outb, int N) {
    int t = threadIdx.x;
    int lane = t & 63;
    int v = blockIdx.x * 4 + (t >> 6);
    if (v >= N) return;
    int g = lane >> 4;
    int l16 = lane & 15;
    int beg = offsets[v], end = offsets[v + 1];

    float acc[8] = {0.f, 0.f, 0.f, 0.f, 0.f, 0.f, 0.f, 0.f};
    int i = beg + g;
    bool v0 = i < end;
    unsigned st0 = v0 ? csr[i] : 0u;
    uint4 pv0 = make_uint4(0, 0, 0, 0);
    if (v0) {
        const unsigned short* row = hr + ((size_t)((st0 >> 16) & 3) * N + (st0 & 0xFFFF)) * DIM + l16 * 8;
        pv0 = *reinterpret_cast<const uint4*>(row);
    }
    while (__any(v0)) {
        int i1 = i + 4;
        bool v1 = i1 < end;
        unsigned st1 = v1 ? csr[i1] : 0u;
        uint4 pv1 = make_uint4(0, 0, 0, 0);
        if (v1) {     // issue next row load; independent of the accumulate below
            const unsigned short* row = hr + ((size_t)((st1 >> 16) & 3) * N + (st1 & 0xFFFF)) * DIM + l16 * 8;
            pv1 = *reinterpret_cast<const uint4*>(row);
        }
        if (v0) {
            float w = (float)(st0 >> 18) * (1.0f / 16383.0f);
            acc[0] += w * bflo(pv0.x); acc[1] += w * bfhi(pv0.x);
            acc[2] += w * bflo(pv0.y); acc[3] += w * bfhi(pv0.y);
            acc[4] += w * bflo(pv0.z); acc[5] += w * bfhi(pv0.z);
            acc[6] += w * bflo(pv0.w); acc[7] += w * bfhi(pv0.w);
        }
        i = i1; st0 = st1; pv0 = pv1; v0 = v1;
    }
    #pragma unroll
    for (int j = 0; j < 8; ++j) {
        acc[j] += __shfl_xor(acc[j], 16);
        acc[j] += __shfl_xor(acc[j], 32);
    }
    if (g == 0) {
        if (BF16IO) {
            unsigned short* op = outb + (size_t)v * DIM + l16 * 8;
            uint4 cur = *reinterpret_cast<const uint4*>(op);
            float r0 = bflo(cur.x) + acc[0], r1 = bfhi(cur.x) + acc[1];
            float r2 = bflo(cur.y) + acc[2], r3 = bfhi(cur.y) + acc[3];
            float r4 = bflo(cur.z) + acc[4], r5 = bfhi(cur.z) + acc[5];
            float r6 = bflo(cur.w) + acc[6], r7 = bfhi(cur.w) + acc[7];
            uint4 o;
            o.x = (unsigned)f2bf(r0) | ((unsigned)f2bf(r1) << 16);
            o.y = (unsigned)f2bf(r2) | ((unsigned)f2bf(r3) << 16);
            o.z = (unsigned)f2bf(r4) | ((unsigned)f2bf(r5) << 16);
            o.w = (unsigned)f2bf(r6) | ((unsigned)f2bf(r7) << 16);
            *reinterpret_cast<uint4*>(op) = o;
        } else {
            float* op = outf + (size_t)v * DIM + l16 * 8;
            float4 c0 = *reinterpret_cast<float4*>(op);
            float4 c1 = *reinterpret_cast<float4*>(op + 4);
            c0.x += acc[0]; c0.y += acc[1]; c0.z += acc[2]; c0.w += acc[3];
            c1.x += acc[4]; c1.y += acc[5]; c1.z += acc[6]; c1.w += acc[7];
            *reinterpret_cast<float4*>(op) = c0;
            *reinterpret_cast<float4*>(op + 4) = c1;
        }
    }
}

// ---------------------------------------------------------------------------
extern "C" void kernel_launch(void* const* d_in, const int* in_sizes, int n_in,
                              void* d_out, int out_size, void* d_ws, size_t ws_size,
                              hipStream_t stream) {
    const float* x       = (const float*)d_in[0];
    const int*   eidx    = (const int*)d_in[1];
    const int*   etype   = (const int*)d_in[2];
    const float* ew      = (const float*)d_in[3];
    const float* w_rel   = (const float*)d_in[4];
    const float* w_root  = (const float*)d_in[5];
    const float* b_conv  = (const float*)d_in[6];
    const float* w_skip  = (const float*)d_in[7];
    const float* b_skip  = (const float*)d_in[8];

    const int N = in_sizes[0] / DIM;          // 50000
    const int E = in_sizes[3];                // 600000
    const int* src = eidx;
    const int* dst = eidx + E;
    const int nblk = (N + 255) / 256;         // 196

    // ---- workspace carve ----
    char* w = (char*)d_ws;
    unsigned short* WTf  = (unsigned short*)w;  w += (size_t)2 * 5 * DIM * DIM * 2;
    unsigned short* xb   = (unsigned short*)w;  w += (size_t)N * DIM * 2;            // 12.8MB
    unsigned short* hr   = (unsigned short*)w;  w += (size_t)3 * N * DIM * 2;        // 38.4MB
    unsigned short* h1   = (unsigned short*)w;  w += (size_t)N * DIM * 2;            // 12.8MB
    int* counts          = (int*)w;             w += (size_t)N * 4;
    int* offsets         = (int*)w;             w += (size_t)(N + 4) * 4;
    int* bsums           = (int*)w;             w += (size_t)256 * 4;
    int* bpre            = (int*)w;             w += (size_t)256 * 4;
    unsigned short* rank = (unsigned short*)w;  w += (size_t)E * 2;                  // 1.2MB
    unsigned* csr        = (unsigned*)w;        w += (size_t)E * 4;                  // 2.4MB

    float* out = (float*)d_out;

    const int n8 = N * DIM / 8;
    zero_kernel<<<(N / 4 + 255) / 256, 256, 0, stream>>>((int4*)counts, N / 4);
    fat_prep<<<K2_CONVB + K2_PREPB + K2_CNTB, 256, 0, stream>>>(
        x, xb, n8, w_rel, w_root, w_skip, WTf, dst, counts, rank, E);
    bsum_kernel<<<nblk, 256, 0, stream>>>(counts, bsums, N);
    bscan_kernel<<<1, 256, 0, stream>>>(bsums, bpre, nblk);
    scan_final<<<nblk, 256, 0, stream>>>(counts, bpre, offsets, N, E);

    int GB = (N + 63) / 64;                   // 782 gemm blocks
    int ablocks = (N + 3) / 4;
    // ---- layer 0 gemm (root+skip merged; bf16 out) overlapped with scatter
    gemm0_scatter<<<GB + K6_SCTB, 256, 0, stream>>>(
        xb, WTf, b_conv, b_skip, hr, h1, N, GB,
        src, dst, etype, ew, offsets, rank, csr, E);
    agg_kernel<true><<<ablocks, 256, 0, stream>>>(hr, csr, offsets, nullptr, h1, N);
    // ---- layer 1 (root from h1, skip from xb; f32 out) ----
    gemm1_kernel<<<GB, 256, 0, stream>>>(h1, xb, WTf + (size_t)5 * DIM * DIM,
                                         b_conv + DIM, b_skip + DIM, hr, out, N);
    agg_kernel<false><<<ablocks, 256, 0, stream>>>(hr, csr, offsets, out, nullptr, N);
}

// Round 9
// 180.045 us; speedup vs baseline: 1.0126x; 1.0126x over previous
//
#include <hip/hip_runtime.h>

// ---------------------------------------------------------------------------
// WRGCN round 9:
//  - REVERT fp8 hr (absmax 1.31 > 0.815; e4m3 too coarse over 12-edge sums
//    compounded x2 layers). hr back to bf16 (R6 = 171us, absmax 0.25).
//  - NEW: slot-split gemm blocks. R7 showed per-wave dual-chain ILP is
//    essential; R6's grid (903 blocks) capped occupancy at ~44%. Split each
//    gemm tile's slots across 2 blocks (gemm0: {0,1},{2,3}; gemm1:
//    {0,1},{2,3,4}) -> 2x blocks, same 128-row dual-chain per wave.
// ---------------------------------------------------------------------------

#define DIM 128

typedef short short8 __attribute__((ext_vector_type(8)));
typedef float f32x4 __attribute__((ext_vector_type(4)));

__device__ __forceinline__ unsigned short f2bf(float f) {
    unsigned u = __float_as_uint(f);
    unsigned r = (u + 0x7FFFu + ((u >> 16) & 1u)) >> 16;   // RNE
    return (unsigned short)r;
}
__device__ __forceinline__ float bflo(unsigned p) { return __uint_as_float(p << 16); }
__device__ __forceinline__ float bfhi(unsigned p) { return __uint_as_float(p & 0xFFFF0000u); }

// ---------------- zero counts (int4 stores) --------------------------------
__global__ void zero_kernel(int4* __restrict__ p, int n4) {
    int i = blockIdx.x * 256 + threadIdx.x;
    if (i < n4) p[i] = make_int4(0, 0, 0, 0);
}

// ---------------- fat kernel 1: conv_bf16 | prep_w | count+rank ------------
#define K2_CONVB 2048
#define K2_PREPB 256
#define K2_CNTB  512

__device__ void conv_body(const float* __restrict__ in, unsigned short* __restrict__ ob,
                          int n8, int bid) {
    for (int i = bid * 256 + threadIdx.x; i < n8; i += K2_CONVB * 256) {
        const float4* ip = reinterpret_cast<const float4*>(in) + (size_t)i * 2;
        float4 v0 = ip[0], v1 = ip[1];
        uint4 o;
        o.x = (unsigned)f2bf(v0.x) | ((unsigned)f2bf(v0.y) << 16);
        o.y = (unsigned)f2bf(v0.z) | ((unsigned)f2bf(v0.w) << 16);
        o.z = (unsigned)f2bf(v1.x) | ((unsigned)f2bf(v1.y) << 16);
        o.w = (unsigned)f2bf(v1.z) | ((unsigned)f2bf(v1.w) << 16);
        reinterpret_cast<uint4*>(ob)[i] = o;
    }
}

// WTf[l][slot][n][ks][lane][j]: value = W_slot[k = ks*32+(lane>>4)*8+j][col = n*16+(lane&15)]
// slot 0..2 = w_rel[r]; slot 3 = w_root (+ w_skip if l==0); slot 4 = w_skip
__device__ void prep_body(const float* __restrict__ w_rel, const float* __restrict__ w_root,
                          const float* __restrict__ w_skip, unsigned short* __restrict__ WTf,
                          int bid) {
    for (int i = bid * 256 + threadIdx.x; i < 2 * 5 * DIM * DIM; i += K2_PREPB * 256) {
        int j    = i & 7;
        int lane = (i >> 3) & 63;
        int ks   = (i >> 9) & 3;
        int n    = (i >> 11) & 7;
        int s    = (i >> 14) % 5;
        int l    = i / (5 * DIM * DIM);
        int col = n * 16 + (lane & 15);
        int k   = ks * 32 + (lane >> 4) * 8 + j;
        float v;
        if (s < 3)       v = w_rel[(((size_t)l * 3 + s) * DIM + k) * DIM + col];
        else if (s == 3) {
            v = w_root[((size_t)l * DIM + k) * DIM + col];
            if (l == 0) v += w_skip[((size_t)k) * DIM + col];
        } else           v = w_skip[((size_t)l * DIM + k) * DIM + col];
        WTf[i] = f2bf(v);
    }
}

__device__ void count_body(const int* __restrict__ dst, int* __restrict__ counts,
                           unsigned short* __restrict__ rank, int E, int bid) {
    for (int i = bid * 256 + threadIdx.x; i < E; i += K2_CNTB * 256) {
        int r = atomicAdd(&counts[dst[i]], 1);
        rank[i] = (unsigned short)r;
    }
}

__global__ __launch_bounds__(256) void fat_prep(
    const float* __restrict__ x, unsigned short* __restrict__ xb, int n8,
    const float* __restrict__ w_rel, const float* __restrict__ w_root,
    const float* __restrict__ w_skip, unsigned short* __restrict__ WTf,
    const int* __restrict__ dst, int* __restrict__ counts,
    unsigned short* __restrict__ rank, int E) {
    int b = blockIdx.x;
    if (b < K2_CONVB)                 conv_body(x, xb, n8, b);
    else if (b < K2_CONVB + K2_PREPB) prep_body(w_rel, w_root, w_skip, WTf, b - K2_CONVB);
    else                              count_body(dst, counts, rank, E, b - K2_CONVB - K2_PREPB);
}

// ---------------- scan ------------------------------------------------------
__global__ void bsum_kernel(const int* __restrict__ counts, int* __restrict__ bsums, int n) {
    int t = threadIdx.x;
    int i = blockIdx.x * 256 + t;
    int v = (i < n) ? counts[i] : 0;
    for (int d = 32; d; d >>= 1) v += __shfl_down(v, d);
    __shared__ int ws[4];
    if ((t & 63) == 0) ws[t >> 6] = v;
    __syncthreads();
    if (t == 0) bsums[blockIdx.x] = ws[0] + ws[1] + ws[2] + ws[3];
}

__global__ void bscan_kernel(const int* __restrict__ bsums, int* __restrict__ bpre, int nblk) {
    __shared__ int s[256];
    int t = threadIdx.x;
    int v = (t < nblk) ? bsums[t] : 0;
    s[t] = v;
    __syncthreads();
    for (int d = 1; d < 256; d <<= 1) {
        int u = (t >= d) ? s[t - d] : 0;
        __syncthreads();
        s[t] += u;
        __syncthreads();
    }
    bpre[t] = s[t] - v;
}

__global__ void scan_final(const int* __restrict__ counts, const int* __restrict__ bpre,
                           int* __restrict__ offsets, int n, int E) {
    __shared__ int s[256];
    int t = threadIdx.x;
    int i = blockIdx.x * 256 + t;
    int v = (i < n) ? counts[i] : 0;
    s[t] = v;
    __syncthreads();
    for (int d = 1; d < 256; d <<= 1) {
        int u = (t >= d) ? s[t - d] : 0;
        __syncthreads();
        s[t] += u;
        __syncthreads();
    }
    int ex = s[t] - v + bpre[blockIdx.x];
    if (i < n) offsets[i] = ex;
    if (i == 0) offsets[n] = E;
}

// ---------------- LDS-free fused GEMM body (slot range [S0, S0+NS)) --------
// 4 waves x 32 rows = 128 rows/block, dual accumulator chains per wave.
// B-frags from fragment-linear WTf (L2-hot), A/X-frags direct bf16 loads.
template<int S0, int NS, bool L1>
__device__ void gemm_body(
    int bid,
    const unsigned short* __restrict__ Ab, const unsigned short* __restrict__ Xb,
    const unsigned short* __restrict__ WTf,
    const float* __restrict__ bconv, const float* __restrict__ bskip,
    unsigned short* __restrict__ hr, void* __restrict__ outp, int M) {
    constexpr int NF = NS * 8;
    int t = threadIdx.x, lane = t & 63, wid = t >> 6;
    int lrow = lane & 15, lhi = lane >> 4;
    int r0 = bid * 128 + wid * 32;

    short8 af[2][4];
    #pragma unroll
    for (int rg = 0; rg < 2; ++rg) {
        int r = r0 + rg * 16 + lrow;
        const unsigned short* ap = Ab + (size_t)(r < M ? r : 0) * DIM + lhi * 8;
        #pragma unroll
        for (int ks = 0; ks < 4; ++ks)
            af[rg][ks] = *reinterpret_cast<const short8*>(ap + ks * 32);
    }
    short8 xf[2][4];        // L1 slot-4 only (loaded at slot-3 entry)
    f32x4 acc34[2][8];      // L1: persists slot3 -> slot4

    short8 b0[4], b1[4];
    auto loadB = [&](int fil, short8* bb) {
        const unsigned short* p = WTf + ((size_t)(S0 * 8 + fil) * 4 * 64 + lane) * 8;
        #pragma unroll
        for (int ks = 0; ks < 4; ++ks)
            bb[ks] = *reinterpret_cast<const short8*>(p + ks * 512);
    };
    loadB(0, b0);
    #pragma unroll
    for (int fil = 0; fil < NF; ++fil) {
        short8* bc = (fil & 1) ? b1 : b0;
        short8* bn = (fil & 1) ? b0 : b1;
        if (fil + 1 < NF) loadB(fil + 1, bn);
        const int slot = S0 + (fil >> 3), n = fil & 7;
        const int col = n * 16 + lrow;
        if (L1 && slot == 3 && n == 0) {
            #pragma unroll
            for (int rg = 0; rg < 2; ++rg) {
                int r = r0 + rg * 16 + lrow;
                const unsigned short* xp = Xb + (size_t)(r < M ? r : 0) * DIM + lhi * 8;
                #pragma unroll
                for (int ks = 0; ks < 4; ++ks)
                    xf[rg][ks] = *reinterpret_cast<const short8*>(xp + ks * 32);
            }
        }
        if (slot < 3) {
            f32x4 a0 = {0.f, 0.f, 0.f, 0.f}, a1 = {0.f, 0.f, 0.f, 0.f};
            #pragma unroll
            for (int ks = 0; ks < 4; ++ks) {
                a0 = __builtin_amdgcn_mfma_f32_16x16x32_bf16(af[0][ks], bc[ks], a0, 0, 0, 0);
                a1 = __builtin_amdgcn_mfma_f32_16x16x32_bf16(af[1][ks], bc[ks], a1, 0, 0, 0);
            }
            unsigned short* hp = hr + (size_t)slot * M * DIM;
            #pragma unroll
            for (int rg = 0; rg < 2; ++rg) {
                f32x4& aa = rg ? a1 : a0;
                #pragma unroll
                for (int i2 = 0; i2 < 4; ++i2) {
                    int r = r0 + rg * 16 + lhi * 4 + i2;
                    if (r < M) hp[(size_t)r * DIM + col] = f2bf(aa[i2]);
                }
            }
        } else if (!L1) {                          // layer 0, slot 3: merged root+skip, bf16 out
            f32x4 a0 = {0.f, 0.f, 0.f, 0.f}, a1 = {0.f, 0.f, 0.f, 0.f};
            #pragma unroll
            for (int ks = 0; ks < 4; ++ks) {
                a0 = __builtin_amdgcn_mfma_f32_16x16x32_bf16(af[0][ks], bc[ks], a0, 0, 0, 0);
                a1 = __builtin_amdgcn_mfma_f32_16x16x32_bf16(af[1][ks], bc[ks], a1, 0, 0, 0);
            }
            float bb = bconv[col] + bskip[col];
            unsigned short* op = (unsigned short*)outp;
            #pragma unroll
            for (int rg = 0; rg < 2; ++rg) {
                f32x4& aa = rg ? a1 : a0;
                #pragma unroll
                for (int i2 = 0; i2 < 4; ++i2) {
                    int r = r0 + rg * 16 + lhi * 4 + i2;
                    if (r < M) op[(size_t)r * DIM + col] = f2bf(aa[i2] + bb);
                }
            }
        } else if (slot == 3) {                    // layer 1: hold root result
            f32x4 z = {0.f, 0.f, 0.f, 0.f};
            acc34[0][n] = z; acc34[1][n] = z;
            #pragma unroll
            for (int ks = 0; ks < 4; ++ks) {
                acc34[0][n] = __builtin_amdgcn_mfma_f32_16x16x32_bf16(af[0][ks], bc[ks], acc34[0][n], 0, 0, 0);
                acc34[1][n] = __builtin_amdgcn_mfma_f32_16x16x32_bf16(af[1][ks], bc[ks], acc34[1][n], 0, 0, 0);
            }
        } else {                                   // layer 1, slot 4: += skip, store f32
            #pragma unroll
            for (int ks = 0; ks < 4; ++ks) {
                acc34[0][n] = __builtin_amdgcn_mfma_f32_16x16x32_bf16(xf[0][ks], bc[ks], acc34[0][n], 0, 0, 0);
                acc34[1][n] = __builtin_amdgcn_mfma_f32_16x16x32_bf16(xf[1][ks], bc[ks], acc34[1][n], 0, 0, 0);
            }
            float bb = bconv[col] + bskip[col];
            float* op = (float*)outp;
            #pragma unroll
            for (int rg = 0; rg < 2; ++rg) {
                #pragma unroll
                for (int i2 = 0; i2 < 4; ++i2) {
                    int r = r0 + rg * 16 + lhi * 4 + i2;
                    if (r < M) op[(size_t)r * DIM + col] = acc34[rg][n][i2] + bb;
                }
            }
        }
    }
}

// ---------------- fat kernel 2: gemm0(x2 slot groups) | scatter ------------
#define K6_SCTB 512

// packed record: src(16) | rel(2)<<16 | wq(14)<<18, wq = round(w*16383)
__device__ void scatter_body(const int* __restrict__ src, const int* __restrict__ dst,
                             const int* __restrict__ etype, const float* __restrict__ ew,
                             const int* __restrict__ offsets,
                             const unsigned short* __restrict__ rank,
                             unsigned* __restrict__ csr, int E, int bid) {
    for (int i = bid * 256 + threadIdx.x; i < E; i += K6_SCTB * 256) {
        int d = dst[i];
        int p = offsets[d] + rank[i];
        unsigned wq = (unsigned)__float2uint_rn(ew[i] * 16383.0f);
        csr[p] = (unsigned)src[i] | ((unsigned)etype[i] << 16) | (wq << 18);
    }
}

__global__ __launch_bounds__(256) void gemm0_scatter(
    const unsigned short* __restrict__ Ab, const unsigned short* __restrict__ WTf,
    const float* __restrict__ bconv, const float* __restrict__ bskip,
    unsigned short* __restrict__ hr, unsigned short* __restrict__ h1, int M, int GB,
    const int* __restrict__ src, const int* __restrict__ dst,
    const int* __restrict__ etype, const float* __restrict__ ew,
    const int* __restrict__ offsets, const unsigned short* __restrict__ rank,
    unsigned* __restrict__ csr, int E) {
    int b = blockIdx.x;
    if (b < GB)          gemm_body<0, 2, false>(b, Ab, nullptr, WTf, bconv, bskip, hr, h1, M);
    else if (b < 2 * GB) gemm_body<2, 2, false>(b - GB, Ab, nullptr, WTf, bconv, bskip, hr, h1, M);
    else                 scatter_body(src, dst, etype, ew, offsets, rank, csr, E, b - 2 * GB);
}

__global__ __launch_bounds__(256) void gemm1_kernel(
    const unsigned short* __restrict__ Ab, const unsigned short* __restrict__ Xb,
    const unsigned short* __restrict__ WTf,
    const float* __restrict__ bconv, const float* __restrict__ bskip,
    unsigned short* __restrict__ hr, float* __restrict__ outp, int M, int GB) {
    int b = blockIdx.x;
    if (b < GB) gemm_body<0, 2, true>(b, Ab, Xb, WTf, bconv, bskip, hr, outp, M);
    else        gemm_body<2, 3, true>(b - GB, Ab, Xb, WTf, bconv, bskip, hr, outp, M);
}

// ---------------- aggregation: 4 edges in flight per wave ------------------
// BF16IO: base/out buffer is bf16 (layer 0); else f32 (layer 1, d_out).
template<bool BF16IO>
__global__ __launch_bounds__(256) void agg_kernel(
    const unsigned short* __restrict__ hr, const unsigned* __restrict__ csr,
    const int* __restrict__ offsets, float* __restrict__ outf,
    unsigned short* __restrict__ outb, int N) {
    int t = threadIdx.x;
    int lane = t & 63;
    int v = blockIdx.x * 4 + (t >> 6);
    if (v >= N) return;
    int g = lane >> 4;
    int l16 = lane & 15;
    int beg = offsets[v], end = offsets[v + 1];

    float acc[8] = {0.f, 0.f, 0.f, 0.f, 0.f, 0.f, 0.f, 0.f};
    int i = beg + g;
    bool valid = i < end;
    unsigned st = valid ? csr[i] : 0u;
    while (__any(valid)) {
        int ni = i + 4;
        bool nv = ni < end;
        unsigned nst = nv ? csr[ni] : 0u;          // prefetch next descriptor
        if (valid) {
            int srcn = st & 0xFFFF;
            int rel  = (st >> 16) & 3;
            float w  = (float)(st >> 18) * (1.0f / 16383.0f);
            const unsigned short* row = hr + ((size_t)rel * N + srcn) * DIM + l16 * 8;
            uint4 pv = *reinterpret_cast<const uint4*>(row);
            acc[0] += w * bflo(pv.x); acc[1] += w * bfhi(pv.x);
            acc[2] += w * bflo(pv.y); acc[3] += w * bfhi(pv.y);
            acc[4] += w * bflo(pv.z); acc[5] += w * bfhi(pv.z);
            acc[6] += w * bflo(pv.w); acc[7] += w * bfhi(pv.w);
        }
        i = ni; st = nst; valid = nv;
    }
    #pragma unroll
    for (int j = 0; j < 8; ++j) {
        acc[j] += __shfl_xor(acc[j], 16);
        acc[j] += __shfl_xor(acc[j], 32);
    }
    if (g == 0) {
        if (BF16IO) {
            unsigned short* op = outb + (size_t)v * DIM + l16 * 8;
            uint4 cur = *reinterpret_cast<const uint4*>(op);
            float r0 = bflo(cur.x) + acc[0], r1 = bfhi(cur.x) + acc[1];
            float r2 = bflo(cur.y) + acc[2], r3 = bfhi(cur.y) + acc[3];
            float r4 = bflo(cur.z) + acc[4], r5 = bfhi(cur.z) + acc[5];
            float r6 = bflo(cur.w) + acc[6], r7 = bfhi(cur.w) + acc[7];
            uint4 o;
            o.x = (unsigned)f2bf(r0) | ((unsigned)f2bf(r1) << 16);
            o.y = (unsigned)f2bf(r2) | ((unsigned)f2bf(r3) << 16);
            o.z = (unsigned)f2bf(r4) | ((unsigned)f2bf(r5) << 16);
            o.w = (unsigned)f2bf(r6) | ((unsigned)f2bf(r7) << 16);
            *reinterpret_cast<uint4*>(op) = o;
        } else {
            float* op = outf + (size_t)v * DIM + l16 * 8;
            float4 c0 = *reinterpret_cast<float4*>(op);
            float4 c1 = *reinterpret_cast<float4*>(op + 4);
            c0.x += acc[0]; c0.y += acc[1]; c0.z += acc[2]; c0.w += acc[3];
            c1.x += acc[4]; c1.y += acc[5]; c1.z += acc[6]; c1.w += acc[7];
            *reinterpret_cast<float4*>(op) = c0;
            *reinterpret_cast<float4*>(op + 4) = c1;
        }
    }
}

// ---------------------------------------------------------------------------
extern "C" void kernel_launch(void* const* d_in, const int* in_sizes, int n_in,
                              void* d_out, int out_size, void* d_ws, size_t ws_size,
                              hipStream_t stream) {
    const float* x       = (const float*)d_in[0];
    const int*   eidx    = (const int*)d_in[1];
    const int*   etype   = (const int*)d_in[2];
    const float* ew      = (const float*)d_in[3];
    const float* w_rel   = (const float*)d_in[4];
    const float* w_root  = (const float*)d_in[5];
    const float* b_conv  = (const float*)d_in[6];
    const float* w_skip  = (const float*)d_in[7];
    const float* b_skip  = (const float*)d_in[8];

    const int N = in_sizes[0] / DIM;          // 50000
    const int E = in_sizes[3];                // 600000
    const int* src = eidx;
    const int* dst = eidx + E;
    const int nblk = (N + 255) / 256;         // 196

    // ---- workspace carve ----
    char* w = (char*)d_ws;
    unsigned short* WTf  = (unsigned short*)w;  w += (size_t)2 * 5 * DIM * DIM * 2;
    unsigned short* xb   = (unsigned short*)w;  w += (size_t)N * DIM * 2;            // 12.8MB
    unsigned short* hr   = (unsigned short*)w;  w += (size_t)3 * N * DIM * 2;        // 38.4MB
    unsigned short* h1   = (unsigned short*)w;  w += (size_t)N * DIM * 2;            // 12.8MB
    int* counts          = (int*)w;             w += (size_t)N * 4;
    int* offsets         = (int*)w;             w += (size_t)(N + 4) * 4;
    int* bsums           = (int*)w;             w += (size_t)256 * 4;
    int* bpre            = (int*)w;             w += (size_t)256 * 4;
    unsigned short* rank = (unsigned short*)w;  w += (size_t)E * 2;                  // 1.2MB
    unsigned* csr        = (unsigned*)w;        w += (size_t)E * 4;                  // 2.4MB

    float* out = (float*)d_out;

    const int n8 = N * DIM / 8;
    zero_kernel<<<(N / 4 + 255) / 256, 256, 0, stream>>>((int4*)counts, N / 4);
    fat_prep<<<K2_CONVB + K2_PREPB + K2_CNTB, 256, 0, stream>>>(
        x, xb, n8, w_rel, w_root, w_skip, WTf, dst, counts, rank, E);
    bsum_kernel<<<nblk, 256, 0, stream>>>(counts, bsums, N);
    bscan_kernel<<<1, 256, 0, stream>>>(bsums, bpre, nblk);
    scan_final<<<nblk, 256, 0, stream>>>(counts, bpre, offsets, N, E);

    int GB = (N + 127) / 128;                 // 391 row tiles
    int ablocks = (N + 3) / 4;
    // ---- layer 0: 2 slot-group gemm blocks per tile, overlapped with scatter
    gemm0_scatter<<<2 * GB + K6_SCTB, 256, 0, stream>>>(
        xb, WTf, b_conv, b_skip, hr, h1, N, GB,
        src, dst, etype, ew, offsets, rank, csr, E);
    agg_kernel<true><<<ablocks, 256, 0, stream>>>(hr, csr, offsets, nullptr, h1, N);
    // ---- layer 1: slot groups {0,1} and {2,3,4} ----
    gemm1_kernel<<<2 * GB, 256, 0, stream>>>(h1, xb, WTf + (size_t)5 * DIM * DIM,
                                             b_conv + DIM, b_skip + DIM, hr, out, N, GB);
    agg_kernel<false><<<ablocks, 256, 0, stream>>>(hr, csr, offsets, out, nullptr, N);
}

// Round 10
// 159.401 us; speedup vs baseline: 1.1437x; 1.1295x over previous
//
#include <hip/hip_runtime.h>

// ---------------------------------------------------------------------------
// WRGCN round 10:
//  - REVERT slot-split (R9: 180us; occupancy-boosting hurts — 2 rounds of
//    evidence). Back to R6 structure (171us known-best).
//  - NEW: LDS-staged coalesced bf16 stores. Direct hr/h1 stores wrote 32B
//    chunks (16 cols x 2B) -> ~1.6x sector write amplification (79MB vs
//    53.6MB logical). Stage wave-private 32x128 tile in LDS, flush as
//    4-row x 256B = 1KB contiguous per instruction. f32 path already 64B.
// ---------------------------------------------------------------------------

#define DIM 128

typedef short short8 __attribute__((ext_vector_type(8)));
typedef float f32x4 __attribute__((ext_vector_type(4)));

__device__ __forceinline__ unsigned short f2bf(float f) {
    unsigned u = __float_as_uint(f);
    unsigned r = (u + 0x7FFFu + ((u >> 16) & 1u)) >> 16;   // RNE
    return (unsigned short)r;
}
__device__ __forceinline__ float bflo(unsigned p) { return __uint_as_float(p << 16); }
__device__ __forceinline__ float bfhi(unsigned p) { return __uint_as_float(p & 0xFFFF0000u); }

// ---------------- zero counts (int4 stores) --------------------------------
__global__ void zero_kernel(int4* __restrict__ p, int n4) {
    int i = blockIdx.x * 256 + threadIdx.x;
    if (i < n4) p[i] = make_int4(0, 0, 0, 0);
}

// ---------------- fat kernel 1: conv_bf16 | prep_w | count+rank ------------
#define K2_CONVB 2048
#define K2_PREPB 256
#define K2_CNTB  512

__device__ void conv_body(const float* __restrict__ in, unsigned short* __restrict__ ob,
                          int n8, int bid) {
    for (int i = bid * 256 + threadIdx.x; i < n8; i += K2_CONVB * 256) {
        const float4* ip = reinterpret_cast<const float4*>(in) + (size_t)i * 2;
        float4 v0 = ip[0], v1 = ip[1];
        uint4 o;
        o.x = (unsigned)f2bf(v0.x) | ((unsigned)f2bf(v0.y) << 16);
        o.y = (unsigned)f2bf(v0.z) | ((unsigned)f2bf(v0.w) << 16);
        o.z = (unsigned)f2bf(v1.x) | ((unsigned)f2bf(v1.y) << 16);
        o.w = (unsigned)f2bf(v1.z) | ((unsigned)f2bf(v1.w) << 16);
        reinterpret_cast<uint4*>(ob)[i] = o;
    }
}

// WTf[l][slot][n][ks][lane][j]: value = W_slot[k = ks*32+(lane>>4)*8+j][col = n*16+(lane&15)]
// slot 0..2 = w_rel[r]; slot 3 = w_root (+ w_skip if l==0); slot 4 = w_skip
__device__ void prep_body(const float* __restrict__ w_rel, const float* __restrict__ w_root,
                          const float* __restrict__ w_skip, unsigned short* __restrict__ WTf,
                          int bid) {
    for (int i = bid * 256 + threadIdx.x; i < 2 * 5 * DIM * DIM; i += K2_PREPB * 256) {
        int j    = i & 7;
        int lane = (i >> 3) & 63;
        int ks   = (i >> 9) & 3;
        int n    = (i >> 11) & 7;
        int s    = (i >> 14) % 5;
        int l    = i / (5 * DIM * DIM);
        int col = n * 16 + (lane & 15);
        int k   = ks * 32 + (lane >> 4) * 8 + j;
        float v;
        if (s < 3)       v = w_rel[(((size_t)l * 3 + s) * DIM + k) * DIM + col];
        else if (s == 3) {
            v = w_root[((size_t)l * DIM + k) * DIM + col];
            if (l == 0) v += w_skip[((size_t)k) * DIM + col];
        } else           v = w_skip[((size_t)l * DIM + k) * DIM + col];
        WTf[i] = f2bf(v);
    }
}

__device__ void count_body(const int* __restrict__ dst, int* __restrict__ counts,
                           unsigned short* __restrict__ rank, int E, int bid) {
    for (int i = bid * 256 + threadIdx.x; i < E; i += K2_CNTB * 256) {
        int r = atomicAdd(&counts[dst[i]], 1);
        rank[i] = (unsigned short)r;
    }
}

__global__ __launch_bounds__(256) void fat_prep(
    const float* __restrict__ x, unsigned short* __restrict__ xb, int n8,
    const float* __restrict__ w_rel, const float* __restrict__ w_root,
    const float* __restrict__ w_skip, unsigned short* __restrict__ WTf,
    const int* __restrict__ dst, int* __restrict__ counts,
    unsigned short* __restrict__ rank, int E) {
    int b = blockIdx.x;
    if (b < K2_CONVB)                 conv_body(x, xb, n8, b);
    else if (b < K2_CONVB + K2_PREPB) prep_body(w_rel, w_root, w_skip, WTf, b - K2_CONVB);
    else                              count_body(dst, counts, rank, E, b - K2_CONVB - K2_PREPB);
}

// ---------------- scan ------------------------------------------------------
__global__ void bsum_kernel(const int* __restrict__ counts, int* __restrict__ bsums, int n) {
    int t = threadIdx.x;
    int i = blockIdx.x * 256 + t;
    int v = (i < n) ? counts[i] : 0;
    for (int d = 32; d; d >>= 1) v += __shfl_down(v, d);
    __shared__ int ws[4];
    if ((t & 63) == 0) ws[t >> 6] = v;
    __syncthreads();
    if (t == 0) bsums[blockIdx.x] = ws[0] + ws[1] + ws[2] + ws[3];
}

__global__ void bscan_kernel(const int* __restrict__ bsums, int* __restrict__ bpre, int nblk) {
    __shared__ int s[256];
    int t = threadIdx.x;
    int v = (t < nblk) ? bsums[t] : 0;
    s[t] = v;
    __syncthreads();
    for (int d = 1; d < 256; d <<= 1) {
        int u = (t >= d) ? s[t - d] : 0;
        __syncthreads();
        s[t] += u;
        __syncthreads();
    }
    bpre[t] = s[t] - v;
}

__global__ void scan_final(const int* __restrict__ counts, const int* __restrict__ bpre,
                           int* __restrict__ offsets, int n, int E) {
    __shared__ int s[256];
    int t = threadIdx.x;
    int i = blockIdx.x * 256 + t;
    int v = (i < n) ? counts[i] : 0;
    s[t] = v;
    __syncthreads();
    for (int d = 1; d < 256; d <<= 1) {
        int u = (t >= d) ? s[t - d] : 0;
        __syncthreads();
        s[t] += u;
        __syncthreads();
    }
    int ex = s[t] - v + bpre[blockIdx.x];
    if (i < n) offsets[i] = ex;
    if (i == 0) offsets[n] = E;
}

// ---------------- LDS-free fused GEMM body ---------------------------------
// 4 waves x 32 rows = 128 rows/block, dual accumulator chains per wave.
// B-frags from fragment-linear WTf (L2-hot), A/X-frags direct bf16 loads.
// bf16 outputs (hr slots, layer-0 h1) staged in wave-private LDS and flushed
// as 1KB-contiguous row stores (fixes 32B-chunk sector write amplification).
template<bool HAS_SKIP>
__device__ void gemm_body(
    int bid,
    const unsigned short* __restrict__ Ab, const unsigned short* __restrict__ Xb,
    const unsigned short* __restrict__ WTf,
    const float* __restrict__ bconv, const float* __restrict__ bskip,
    unsigned short* __restrict__ hr, void* __restrict__ outp, int M) {
    constexpr int NF = HAS_SKIP ? 40 : 32;
    __shared__ unsigned short stile[4][32][136];   // wave-private 32x128 (+pad)
    int t = threadIdx.x, lane = t & 63, wid = t >> 6;
    int lrow = lane & 15, lhi = lane >> 4;
    int r0 = bid * 128 + wid * 32;

    short8 af[2][4];
    #pragma unroll
    for (int rg = 0; rg < 2; ++rg) {
        int r = r0 + rg * 16 + lrow;
        const unsigned short* ap = Ab + (size_t)(r < M ? r : 0) * DIM + lhi * 8;
        #pragma unroll
        for (int ks = 0; ks < 4; ++ks)
            af[rg][ks] = *reinterpret_cast<const short8*>(ap + ks * 32);
    }
    short8 xf[2][4];        // HAS_SKIP only (loaded at slot-3 entry)
    f32x4 acc34[2][8];      // HAS_SKIP: persists slot3 -> slot4

    // coalesced flush of one staged bf16 slot tile: 8 insts x 1KB contiguous
    auto flush = [&](unsigned short* gbase) {
        #pragma unroll
        for (int j = 0; j < 8; ++j) {
            int lr = j * 4 + lhi;                  // local row 0..31
            int lc = lrow * 8;                     // 16B col chunk
            int gr = r0 + lr;
            if (gr < M)
                *reinterpret_cast<uint4*>(gbase + (size_t)gr * DIM + lc) =
                    *reinterpret_cast<const uint4*>(&stile[wid][lr][lc]);
        }
    };

    short8 b0[4], b1[4];
    auto loadB = [&](int fi, short8* bb) {
        const unsigned short* p = WTf + ((size_t)fi * 4 * 64 + lane) * 8;
        #pragma unroll
        for (int ks = 0; ks < 4; ++ks)
            bb[ks] = *reinterpret_cast<const short8*>(p + ks * 512);
    };
    loadB(0, b0);
    #pragma unroll
    for (int fi = 0; fi < NF; ++fi) {
        short8* bc = (fi & 1) ? b1 : b0;
        short8* bn = (fi & 1) ? b0 : b1;
        if (fi + 1 < NF) loadB(fi + 1, bn);
        const int slot = fi >> 3, n = fi & 7;
        const int col = n * 16 + lrow;
        if (HAS_SKIP && slot == 3 && n == 0) {
            #pragma unroll
            for (int rg = 0; rg < 2; ++rg) {
                int r = r0 + rg * 16 + lrow;
                const unsigned short* xp = Xb + (size_t)(r < M ? r : 0) * DIM + lhi * 8;
                #pragma unroll
                for (int ks = 0; ks < 4; ++ks)
                    xf[rg][ks] = *reinterpret_cast<const short8*>(xp + ks * 32);
            }
        }
        if (slot < 3) {
            f32x4 a0 = {0.f, 0.f, 0.f, 0.f}, a1 = {0.f, 0.f, 0.f, 0.f};
            #pragma unroll
            for (int ks = 0; ks < 4; ++ks) {
                a0 = __builtin_amdgcn_mfma_f32_16x16x32_bf16(af[0][ks], bc[ks], a0, 0, 0, 0);
                a1 = __builtin_amdgcn_mfma_f32_16x16x32_bf16(af[1][ks], bc[ks], a1, 0, 0, 0);
            }
            #pragma unroll
            for (int rg = 0; rg < 2; ++rg) {
                f32x4& aa = rg ? a1 : a0;
                #pragma unroll
                for (int i2 = 0; i2 < 4; ++i2)
                    stile[wid][rg * 16 + lhi * 4 + i2][col] = f2bf(aa[i2]);
            }
            if (n == 7) flush(hr + (size_t)slot * M * DIM);
        } else if (!HAS_SKIP) {                    // layer 0, slot 3: merged root+skip, bf16 out
            f32x4 a0 = {0.f, 0.f, 0.f, 0.f}, a1 = {0.f, 0.f, 0.f, 0.f};
            #pragma unroll
            for (int ks = 0; ks < 4; ++ks) {
                a0 = __builtin_amdgcn_mfma_f32_16x16x32_bf16(af[0][ks], bc[ks], a0, 0, 0, 0);
                a1 = __builtin_amdgcn_mfma_f32_16x16x32_bf16(af[1][ks], bc[ks], a1, 0, 0, 0);
            }
            float bb = bconv[col] + bskip[col];
            #pragma unroll
            for (int rg = 0; rg < 2; ++rg) {
                f32x4& aa = rg ? a1 : a0;
                #pragma unroll
                for (int i2 = 0; i2 < 4; ++i2)
                    stile[wid][rg * 16 + lhi * 4 + i2][col] = f2bf(aa[i2] + bb);
            }
            if (n == 7) flush((unsigned short*)outp);
        } else if (slot == 3) {                    // layer 1: hold root result
            f32x4 z = {0.f, 0.f, 0.f, 0.f};
            acc34[0][n] = z; acc34[1][n] = z;
            #pragma unroll
            for (int ks = 0; ks < 4; ++ks) {
                acc34[0][n] = __builtin_amdgcn_mfma_f32_16x16x32_bf16(af[0][ks], bc[ks], acc34[0][n], 0, 0, 0);
                acc34[1][n] = __builtin_amdgcn_mfma_f32_16x16x32_bf16(af[1][ks], bc[ks], acc34[1][n], 0, 0, 0);
            }
        } else {                                   // layer 1, slot 4: += skip, store f32
            #pragma unroll
            for (int ks = 0; ks < 4; ++ks) {
                acc34[0][n] = __builtin_amdgcn_mfma_f32_16x16x32_bf16(xf[0][ks], bc[ks], acc34[0][n], 0, 0, 0);
                acc34[1][n] = __builtin_amdgcn_mfma_f32_16x16x32_bf16(xf[1][ks], bc[ks], acc34[1][n], 0, 0, 0);
            }
            float bb = bconv[col] + bskip[col];
            float* op = (float*)outp;              // f32: 64B/16 lanes, already sectored
            #pragma unroll
            for (int rg = 0; rg < 2; ++rg) {
                #pragma unroll
                for (int i2 = 0; i2 < 4; ++i2) {
                    int r = r0 + rg * 16 + lhi * 4 + i2;
                    if (r < M) op[(size_t)r * DIM + col] = acc34[rg][n][i2] + bb;
                }
            }
        }
    }
}

// ---------------- fat kernel 2: gemm0 | scatter ----------------------------
#define K6_SCTB 512

// packed record: src(16) | rel(2)<<16 | wq(14)<<18, wq = round(w*16383)
__device__ void scatter_body(const int* __restrict__ src, const int* __restrict__ dst,
                             const int* __restrict__ etype, const float* __restrict__ ew,
                             const int* __restrict__ offsets,
                             const unsigned short* __restrict__ rank,
                             unsigned* __restrict__ csr, int E, int bid) {
    for (int i = bid * 256 + threadIdx.x; i < E; i += K6_SCTB * 256) {
        int d = dst[i];
        int p = offsets[d] + rank[i];
        unsigned wq = (unsigned)__float2uint_rn(ew[i] * 16383.0f);
        csr[p] = (unsigned)src[i] | ((unsigned)etype[i] << 16) | (wq << 18);
    }
}

__global__ __launch_bounds__(256) void gemm0_scatter(
    const unsigned short* __restrict__ Ab, const unsigned short* __restrict__ WTf,
    const float* __restrict__ bconv, const float* __restrict__ bskip,
    unsigned short* __restrict__ hr, unsigned short* __restrict__ h1, int M, int GB,
    const int* __restrict__ src, const int* __restrict__ dst,
    const int* __restrict__ etype, const float* __restrict__ ew,
    const int* __restrict__ offsets, const unsigned short* __restrict__ rank,
    unsigned* __restrict__ csr, int E) {
    int b = blockIdx.x;
    if (b < GB) gemm_body<false>(b, Ab, nullptr, WTf, bconv, bskip, hr, h1, M);
    else        scatter_body(src, dst, etype, ew, offsets, rank, csr, E, b - GB);
}

__global__ __launch_bounds__(256) void gemm1_kernel(
    const unsigned short* __restrict__ Ab, const unsigned short* __restrict__ Xb,
    const unsigned short* __restrict__ WTf,
    const float* __restrict__ bconv, const float* __restrict__ bskip,
    unsigned short* __restrict__ hr, float* __restrict__ outp, int M) {
    gemm_body<true>(blockIdx.x, Ab, Xb, WTf, bconv, bskip, hr, outp, M);
}

// ---------------- aggregation: 4 edges in flight per wave ------------------
// BF16IO: base/out buffer is bf16 (layer 0); else f32 (layer 1, d_out).
template<bool BF16IO>
__global__ __launch_bounds__(256) void agg_kernel(
    const unsigned short* __restrict__ hr, const unsigned* __restrict__ csr,
    const int* __restrict__ offsets, float* __restrict__ outf,
    unsigned short* __restrict__ outb, int N) {
    int t = threadIdx.x;
    int lane = t & 63;
    int v = blockIdx.x * 4 + (t >> 6);
    if (v >= N) return;
    int g = lane >> 4;
    int l16 = lane & 15;
    int beg = offsets[v], end = offsets[v + 1];

    float acc[8] = {0.f, 0.f, 0.f, 0.f, 0.f, 0.f, 0.f, 0.f};
    int i = beg + g;
    bool valid = i < end;
    unsigned st = valid ? csr[i] : 0u;
    while (__any(valid)) {
        int ni = i + 4;
        bool nv = ni < end;
        unsigned nst = nv ? csr[ni] : 0u;          // prefetch next descriptor
        if (valid) {
            int srcn = st & 0xFFFF;
            int rel  = (st >> 16) & 3;
            float w  = (float)(st >> 18) * (1.0f / 16383.0f);
            const unsigned short* row = hr + ((size_t)rel * N + srcn) * DIM + l16 * 8;
            uint4 pv = *reinterpret_cast<const uint4*>(row);
            acc[0] += w * bflo(pv.x); acc[1] += w * bfhi(pv.x);
            acc[2] += w * bflo(pv.y); acc[3] += w * bfhi(pv.y);
            acc[4] += w * bflo(pv.z); acc[5] += w * bfhi(pv.z);
            acc[6] += w * bflo(pv.w); acc[7] += w * bfhi(pv.w);
        }
        i = ni; st = nst; valid = nv;
    }
    #pragma unroll
    for (int j = 0; j < 8; ++j) {
        acc[j] += __shfl_xor(acc[j], 16);
        acc[j] += __shfl_xor(acc[j], 32);
    }
    if (g == 0) {
        if (BF16IO) {
            unsigned short* op = outb + (size_t)v * DIM + l16 * 8;
            uint4 cur = *reinterpret_cast<const uint4*>(op);
            float r0 = bflo(cur.x) + acc[0], r1 = bfhi(cur.x) + acc[1];
            float r2 = bflo(cur.y) + acc[2], r3 = bfhi(cur.y) + acc[3];
            float r4 = bflo(cur.z) + acc[4], r5 = bfhi(cur.z) + acc[5];
            float r6 = bflo(cur.w) + acc[6], r7 = bfhi(cur.w) + acc[7];
            uint4 o;
            o.x = (unsigned)f2bf(r0) | ((unsigned)f2bf(r1) << 16);
            o.y = (unsigned)f2bf(r2) | ((unsigned)f2bf(r3) << 16);
            o.z = (unsigned)f2bf(r4) | ((unsigned)f2bf(r5) << 16);
            o.w = (unsigned)f2bf(r6) | ((unsigned)f2bf(r7) << 16);
            *reinterpret_cast<uint4*>(op) = o;
        } else {
            float* op = outf + (size_t)v * DIM + l16 * 8;
            float4 c0 = *reinterpret_cast<float4*>(op);
            float4 c1 = *reinterpret_cast<float4*>(op + 4);
            c0.x += acc[0]; c0.y += acc[1]; c0.z += acc[2]; c0.w += acc[3];
            c1.x += acc[4]; c1.y += acc[5]; c1.z += acc[6]; c1.w += acc[7];
            *reinterpret_cast<float4*>(op) = c0;
            *reinterpret_cast<float4*>(op + 4) = c1;
        }
    }
}

// ---------------------------------------------------------------------------
extern "C" void kernel_launch(void* const* d_in, const int* in_sizes, int n_in,
                              void* d_out, int out_size, void* d_ws, size_t ws_size,
                              hipStream_t stream) {
    const float* x       = (const float*)d_in[0];
    const int*   eidx    = (const int*)d_in[1];
    const int*   etype   = (const int*)d_in[2];
    const float* ew      = (const float*)d_in[3];
    const float* w_rel   = (const float*)d_in[4];
    const float* w_root  = (const float*)d_in[5];
    const float* b_conv  = (const float*)d_in[6];
    const float* w_skip  = (const float*)d_in[7];
    const float* b_skip  = (const float*)d_in[8];

    const int N = in_sizes[0] / DIM;          // 50000
    const int E = in_sizes[3];                // 600000
    const int* src = eidx;
    const int* dst = eidx + E;
    const int nblk = (N + 255) / 256;         // 196

    // ---- workspace carve ----
    char* w = (char*)d_ws;
    unsigned short* WTf  = (unsigned short*)w;  w += (size_t)2 * 5 * DIM * DIM * 2;
    unsigned short* xb   = (unsigned short*)w;  w += (size_t)N * DIM * 2;            // 12.8MB
    unsigned short* hr   = (unsigned short*)w;  w += (size_t)3 * N * DIM * 2;        // 38.4MB
    unsigned short* h1   = (unsigned short*)w;  w += (size_t)N * DIM * 2;            // 12.8MB
    int* counts          = (int*)w;             w += (size_t)N * 4;
    int* offsets         = (int*)w;             w += (size_t)(N + 4) * 4;
    int* bsums           = (int*)w;             w += (size_t)256 * 4;
    int* bpre            = (int*)w;             w += (size_t)256 * 4;
    unsigned short* rank = (unsigned short*)w;  w += (size_t)E * 2;                  // 1.2MB
    unsigned* csr        = (unsigned*)w;        w += (size_t)E * 4;                  // 2.4MB

    float* out = (float*)d_out;

    const int n8 = N * DIM / 8;
    zero_kernel<<<(N / 4 + 255) / 256, 256, 0, stream>>>((int4*)counts, N / 4);
    fat_prep<<<K2_CONVB + K2_PREPB + K2_CNTB, 256, 0, stream>>>(
        x, xb, n8, w_rel, w_root, w_skip, WTf, dst, counts, rank, E);
    bsum_kernel<<<nblk, 256, 0, stream>>>(counts, bsums, N);
    bscan_kernel<<<1, 256, 0, stream>>>(bsums, bpre, nblk);
    scan_final<<<nblk, 256, 0, stream>>>(counts, bpre, offsets, N, E);

    int GB = (N + 127) / 128;                 // 391 gemm blocks
    int ablocks = (N + 3) / 4;
    // ---- layer 0 gemm (root+skip merged; bf16 out) overlapped with scatter
    gemm0_scatter<<<GB + K6_SCTB, 256, 0, stream>>>(
        xb, WTf, b_conv, b_skip, hr, h1, N, GB,
        src, dst, etype, ew, offsets, rank, csr, E);
    agg_kernel<true><<<ablocks, 256, 0, stream>>>(hr, csr, offsets, nullptr, h1, N);
    // ---- layer 1 (root from h1, skip from xb; f32 out) ----
    gemm1_kernel<<<GB, 256, 0, stream>>>(h1, xb, WTf + (size_t)5 * DIM * DIM,
                                         b_conv + DIM, b_skip + DIM, hr, out, N);
    agg_kernel<false><<<ablocks, 256, 0, stream>>>(hr, csr, offsets, out, nullptr, N);
}